// Round 1
// baseline (2314.502 us; speedup 1.0000x reference)
//
#include <hip/hip_runtime.h>

#define T_LEN 2048
#define NTHREADS 896   // 14 waves: 7 groups (3 gx-layers + 4 gh-layers) x 2 halves x 64 gates

// Diagonal-wavefront fused 4-layer GRU, fp32.
// Block b = batch row b. Superstep s: layer l computes timestep t = s - l.
// All layer-steps within a superstep depend only on superstep s-1 state -> no
// cross-block sync, no global intermediates.
//
// Thread map (tid 0..895):
//   g2 = tid>>7 in 0..6 : 0..2 = gx-dots for layer g2+1 (input = h[g2])
//                         3..6 = gh-dots for layer g2-3 (input = h[g2-3])
//   c  = (tid&127)>>1   : gate column 0..63
//   half = tid&1        : k-range half (32 of 64)
// Each thread owns dot rows j = {c, 64+c, 128+c} (the r,z,n rows of gate c),
// weights held in 96 registers for the whole kernel.
__global__ __launch_bounds__(NTHREADS, 1)
void gru_fused(const float* __restrict__ x,
               const float* __restrict__ w_ih0,
               const float* __restrict__ w_ih_rest,
               const float* __restrict__ w_hh,
               const float* __restrict__ b_ih,
               const float* __restrict__ b_hh,
               const float* __restrict__ fc_w,
               const float* __restrict__ fc_b,
               float* __restrict__ out)
{
    extern __shared__ float smem[];
    float* xs   = smem;              // 8192 f32: staged x row as float4[2048]
    float* hst  = smem + 8192;       // 4*64 f32: h state per layer
    float* gbuf = smem + 8192 + 256; // 7*192 f32: dot results per group

    const int tid = threadIdx.x;
    const int b   = blockIdx.x;

    // ---- stage this row's x into LDS (contiguous, float4) ----
    {
        const float4* xg = (const float4*)(x + (size_t)b * (T_LEN * 4));
        float4* xd = (float4*)xs;
        for (int i = tid; i < T_LEN; i += NTHREADS) xd[i] = xg[i];
    }
    if (tid < 256) hst[tid] = 0.0f;  // h0 = 0 for all layers

    // ---- dot-thread identity ----
    const int g2   = tid >> 7;          // 0..6
    const int r7   = tid & 127;
    const int c    = r7 >> 1;           // 0..63
    const int half = r7 & 1;            // 0/1
    const int src  = (g2 < 3) ? g2 : (g2 - 3);  // which h[] vector this group reads

    // ---- preload dot weights into registers: 3 rows x 32 k each ----
    float w[3][32];
    {
        const float* wsrc = (g2 < 3) ? (w_ih_rest + g2 * (192 * 64))
                                     : (w_hh      + (g2 - 3) * (192 * 64));
        #pragma unroll
        for (int i = 0; i < 3; ++i) {
            const float4* p = (const float4*)(wsrc + (i * 64 + c) * 64 + half * 32);
            #pragma unroll
            for (int q = 0; q < 8; ++q) {
                float4 f = p[q];
                w[i][q * 4 + 0] = f.x; w[i][q * 4 + 1] = f.y;
                w[i][q * 4 + 2] = f.z; w[i][q * 4 + 3] = f.w;
            }
        }
    }

    // ---- combine-thread preload (tid<256: (layer cl, gate cc)) ----
    const int cl = tid >> 6;
    const int cc = tid & 63;
    float bias[6];
    float w0[12];
    float hreg = 0.0f;
    if (tid < 256) {
        #pragma unroll
        for (int i = 0; i < 3; ++i) {
            bias[i]     = b_ih[cl * 192 + i * 64 + cc];
            bias[3 + i] = b_hh[cl * 192 + i * 64 + cc];
        }
        if (cl == 0) {
            #pragma unroll
            for (int i = 0; i < 3; ++i) {
                const float4 f = *(const float4*)(w_ih0 + (i * 64 + cc) * 4);
                w0[i * 4 + 0] = f.x; w0[i * 4 + 1] = f.y;
                w0[i * 4 + 2] = f.z; w0[i * 4 + 3] = f.w;
            }
        }
    }
    __syncthreads();

    const float* vb = hst + src * 64 + half * 32;

    // ---- main diagonal loop: s = 0 .. T+2 ----
    for (int s = 0; s < T_LEN + 3; ++s) {
        // dot phase: 3 independent 32-FMA chains, v broadcast from LDS
        float a0 = 0.f, a1 = 0.f, a2 = 0.f;
        float v[32];
        #pragma unroll
        for (int q = 0; q < 8; ++q) {
            float4 f = ((const float4*)vb)[q];
            v[q * 4 + 0] = f.x; v[q * 4 + 1] = f.y;
            v[q * 4 + 2] = f.z; v[q * 4 + 3] = f.w;
        }
        #pragma unroll
        for (int k = 0; k < 32; ++k) {
            a0 = fmaf(v[k], w[0][k], a0);
            a1 = fmaf(v[k], w[1][k], a1);
            a2 = fmaf(v[k], w[2][k], a2);
        }
        a0 += __shfl_xor(a0, 1);
        a1 += __shfl_xor(a1, 1);
        a2 += __shfl_xor(a2, 1);
        if (half == 0) {
            gbuf[g2 * 192 +       c] = a0;
            gbuf[g2 * 192 +  64 + c] = a1;
            gbuf[g2 * 192 + 128 + c] = a2;
        }
        __syncthreads();

        // combine phase: 256 threads, one gate each, layer cl at t = s - cl
        if (tid < 256) {
            const int t = s - cl;
            if (t >= 0 && t < T_LEN) {
                float xr, xz, xn;
                if (cl == 0) {
                    const float4 xv = ((const float4*)xs)[t];
                    xr = bias[0] + xv.x * w0[0] + xv.y * w0[1] + xv.z * w0[2]  + xv.w * w0[3];
                    xz = bias[1] + xv.x * w0[4] + xv.y * w0[5] + xv.z * w0[6]  + xv.w * w0[7];
                    xn = bias[2] + xv.x * w0[8] + xv.y * w0[9] + xv.z * w0[10] + xv.w * w0[11];
                } else {
                    xr = bias[0] + gbuf[(cl - 1) * 192 +       cc];
                    xz = bias[1] + gbuf[(cl - 1) * 192 +  64 + cc];
                    xn = bias[2] + gbuf[(cl - 1) * 192 + 128 + cc];
                }
                const float hr = bias[3] + gbuf[(3 + cl) * 192 +       cc];
                const float hz = bias[4] + gbuf[(3 + cl) * 192 +  64 + cc];
                const float hn = bias[5] + gbuf[(3 + cl) * 192 + 128 + cc];

                const float r = 1.0f / (1.0f + __expf(-(xr + hr)));
                const float z = 1.0f / (1.0f + __expf(-(xz + hz)));
                const float e = __expf(2.0f * (xn + r * hn));
                const float n = 1.0f - 2.0f / (e + 1.0f);   // tanh
                const float hnew = n + z * (hreg - n);      // (1-z)*n + z*h
                hreg = hnew;
                hst[cl * 64 + cc] = hnew;
            }
        }
        __syncthreads();
    }

    // ---- fused FC head on layer-3 final h ----
    if (tid < 5) {
        float acc = fc_b[tid];
        const float* wf = fc_w + tid * 64;
        #pragma unroll
        for (int k = 0; k < 64; ++k) acc = fmaf(hst[3 * 64 + k], wf[k], acc);
        out[(size_t)b * 5 + tid] = acc;
    }
}

extern "C" void kernel_launch(void* const* d_in, const int* in_sizes, int n_in,
                              void* d_out, int out_size, void* d_ws, size_t ws_size,
                              hipStream_t stream) {
    const float* x         = (const float*)d_in[0];
    const float* w_ih0     = (const float*)d_in[1];
    const float* w_ih_rest = (const float*)d_in[2];
    const float* w_hh      = (const float*)d_in[3];
    const float* b_ih      = (const float*)d_in[4];
    const float* b_hh      = (const float*)d_in[5];
    const float* fc_w      = (const float*)d_in[6];
    const float* fc_b      = (const float*)d_in[7];

    const size_t lds_bytes = (8192 + 256 + 7 * 192) * sizeof(float);
    gru_fused<<<dim3(256), dim3(NTHREADS), lds_bytes, stream>>>(
        x, w_ih0, w_ih_rest, w_hh, b_ih, b_hh, fc_w, fc_b, (float*)d_out);
}

// Round 2
// 2080.364 us; speedup vs baseline: 1.1125x; 1.1125x over previous
//
#include <hip/hip_runtime.h>

#define T_LEN 2048
#define NTHREADS 896   // 14 waves: 7 groups (3 gx-layers + 4 gh-layers) x 64 gates x 2 halves

// Diagonal-wavefront fused 4-layer GRU, fp32.
// Block b = batch row b. Superstep s: layer l computes timestep t = s - l.
//
// Thread map (tid 0..895):
//   g2 = tid>>7 in 0..6 : 0..2 = gx-dots for layer g2+1 (input = h[g2])
//                         3..6 = gh-dots for layer g2-3 (input = h[g2-3])
//   c  = (tid&127)>>1   : gate column 0..63
//   half = tid&1        : k-range half (32 of 64)
// Each thread owns dot rows {c, 64+c, 128+c} (r,z,n rows of gate c),
// 96 weight floats in registers for the whole kernel. Gate biases are folded
// into the half==0 accumulator init so combine threads carry no extra state.
__global__ __launch_bounds__(NTHREADS, 4)
void gru_fused(const float* __restrict__ x,
               const float* __restrict__ w_ih0,
               const float* __restrict__ w_ih_rest,
               const float* __restrict__ w_hh,
               const float* __restrict__ b_ih,
               const float* __restrict__ b_hh,
               const float* __restrict__ fc_w,
               const float* __restrict__ fc_b,
               float* __restrict__ out)
{
    // LDS layout (floats)
    extern __shared__ float smem[];
    float* xs   = smem;                    // 8192: x row as float4[2048]
    float* hst  = xs + 8192;               // 256:  h state per layer
    float* gbuf = hst + 256;               // 1344: 7*192 dot results (bias included)
    float* w0s  = gbuf + 1344;             // 768:  layer-0 W_ih rows, float4[192]
    float* b0s  = w0s + 768;               // 192:  layer-0 b_ih

    const int tid = threadIdx.x;
    const int b   = blockIdx.x;

    // ---- stage x row, layer-0 weights/bias, zero h ----
    {
        const float4* xg = (const float4*)(x + (size_t)b * (T_LEN * 4));
        float4* xd = (float4*)xs;
        for (int i = tid; i < T_LEN; i += NTHREADS) xd[i] = xg[i];
    }
    if (tid < 256) hst[tid] = 0.0f;
    if (tid >= 256 && tid < 448) ((float4*)w0s)[tid - 256] = ((const float4*)w_ih0)[tid - 256];
    if (tid >= 448 && tid < 640) b0s[tid - 448] = b_ih[tid - 448];

    // ---- dot-thread identity ----
    const int g2   = tid >> 7;                  // 0..6
    const int r7   = tid & 127;
    const int c    = r7 >> 1;                   // 0..63
    const int half = r7 & 1;                    // 0/1
    const int src  = (g2 < 3) ? g2 : (g2 - 3);

    // ---- preload dot weights into registers (float4[3][8] = 96 VGPRs) ----
    float4 w4[3][8];
    float bini[3];
    {
        const float* wsrc;
        const float* bsrc;
        if (g2 < 3) { wsrc = w_ih_rest + g2 * (192 * 64); bsrc = b_ih + (g2 + 1) * 192; }
        else        { wsrc = w_hh + (g2 - 3) * (192 * 64); bsrc = b_hh + (g2 - 3) * 192; }
        #pragma unroll
        for (int i = 0; i < 3; ++i) {
            const float4* p = (const float4*)(wsrc + (i * 64 + c) * 64 + half * 32);
            #pragma unroll
            for (int q = 0; q < 8; ++q) w4[i][q] = p[q];
            bini[i] = (half == 0) ? bsrc[i * 64 + c] : 0.0f;
        }
    }

    const int cl = tid >> 6;      // combine identity (tid<256)
    const int cc = tid & 63;
    __syncthreads();

    const float4* vb4 = (const float4*)(hst + src * 64 + half * 32);

    // ---- main diagonal loop ----
    for (int s = 0; s < T_LEN + 3; ++s) {
        // dot phase: 96 FMAs per thread, h vector broadcast from LDS
        float a0 = bini[0], a1 = bini[1], a2 = bini[2];
        #pragma unroll
        for (int q = 0; q < 8; ++q) {
            const float4 f = vb4[q];
            a0 = fmaf(f.x, w4[0][q].x, a0); a0 = fmaf(f.y, w4[0][q].y, a0);
            a0 = fmaf(f.z, w4[0][q].z, a0); a0 = fmaf(f.w, w4[0][q].w, a0);
            a1 = fmaf(f.x, w4[1][q].x, a1); a1 = fmaf(f.y, w4[1][q].y, a1);
            a1 = fmaf(f.z, w4[1][q].z, a1); a1 = fmaf(f.w, w4[1][q].w, a1);
            a2 = fmaf(f.x, w4[2][q].x, a2); a2 = fmaf(f.y, w4[2][q].y, a2);
            a2 = fmaf(f.z, w4[2][q].z, a2); a2 = fmaf(f.w, w4[2][q].w, a2);
        }
        a0 += __shfl_xor(a0, 1);
        a1 += __shfl_xor(a1, 1);
        a2 += __shfl_xor(a2, 1);
        if (half == 0) {
            gbuf[g2 * 192 +       c] = a0;
            gbuf[g2 * 192 +  64 + c] = a1;
            gbuf[g2 * 192 + 128 + c] = a2;
        }
        __syncthreads();

        // combine phase: 4 waves, one gate each, layer cl at t = s - cl
        if (tid < 256) {
            const int t = s - cl;
            if (t >= 0 && t < T_LEN) {
                float xr, xz, xn;
                if (cl == 0) {
                    const float4 xv = ((const float4*)xs)[t];
                    const float4 u0 = ((const float4*)w0s)[cc];
                    const float4 u1 = ((const float4*)w0s)[64 + cc];
                    const float4 u2 = ((const float4*)w0s)[128 + cc];
                    xr = b0s[cc]       + xv.x * u0.x + xv.y * u0.y + xv.z * u0.z + xv.w * u0.w;
                    xz = b0s[64 + cc]  + xv.x * u1.x + xv.y * u1.y + xv.z * u1.z + xv.w * u1.w;
                    xn = b0s[128 + cc] + xv.x * u2.x + xv.y * u2.y + xv.z * u2.z + xv.w * u2.w;
                } else {
                    xr = gbuf[(cl - 1) * 192 +       cc];
                    xz = gbuf[(cl - 1) * 192 +  64 + cc];
                    xn = gbuf[(cl - 1) * 192 + 128 + cc];
                }
                const float hr = gbuf[(3 + cl) * 192 +       cc];
                const float hz = gbuf[(3 + cl) * 192 +  64 + cc];
                const float hn = gbuf[(3 + cl) * 192 + 128 + cc];
                const float hold = hst[cl * 64 + cc];

                const float r = 1.0f / (1.0f + __expf(-(xr + hr)));
                const float z = 1.0f / (1.0f + __expf(-(xz + hz)));
                const float e = __expf(2.0f * (xn + r * hn));
                const float n = 1.0f - 2.0f / (e + 1.0f);   // tanh
                hst[cl * 64 + cc] = n + z * (hold - n);      // (1-z)*n + z*h
            }
        }
        __syncthreads();
    }

    // ---- fused FC head on layer-3 final h ----
    if (tid < 5) {
        float acc = fc_b[tid];
        const float* wf = fc_w + tid * 64;
        #pragma unroll
        for (int k = 0; k < 64; ++k) acc = fmaf(hst[3 * 64 + k], wf[k], acc);
        out[(size_t)b * 5 + tid] = acc;
    }
}

extern "C" void kernel_launch(void* const* d_in, const int* in_sizes, int n_in,
                              void* d_out, int out_size, void* d_ws, size_t ws_size,
                              hipStream_t stream) {
    const float* x         = (const float*)d_in[0];
    const float* w_ih0     = (const float*)d_in[1];
    const float* w_ih_rest = (const float*)d_in[2];
    const float* w_hh      = (const float*)d_in[3];
    const float* b_ih      = (const float*)d_in[4];
    const float* b_hh      = (const float*)d_in[5];
    const float* fc_w      = (const float*)d_in[6];
    const float* fc_b      = (const float*)d_in[7];

    const size_t lds_bytes = (8192 + 256 + 1344 + 768 + 192) * sizeof(float);
    gru_fused<<<dim3(256), dim3(NTHREADS), lds_bytes, stream>>>(
        x, w_ih0, w_ih_rest, w_hh, b_ih, b_hh, fc_w, fc_b, (float*)d_out);
}

// Round 3
// 1966.806 us; speedup vs baseline: 1.1768x; 1.0577x over previous
//
#include <hip/hip_runtime.h>

#define T_LEN 2048
#define NTHREADS 896   // 14 waves: 7 groups (3 gx-layers + 4 gh-layers) x 64 gates x 2 halves

// Diagonal-wavefront fused 4-layer GRU, fp32, weights register-resident.
// Block b = batch row b. Superstep s: layer l computes timestep t = s - l.
//
// Thread map (tid 0..895):
//   g2 = tid>>7 in 0..6 : 0..2 = gx-dots for layer g2+1 (input = h[g2])
//                         3..6 = gh-dots for layer g2-3 (input = h[g2-3])
//   c  = (tid&127)>>1   : gate column 0..63
//   half = tid&1        : k-range half (32 of 64)
// Each thread owns dot rows {c, 64+c, 128+c} (r,z,n rows of gate c) = 96
// weight floats in VGPRs for the whole kernel. amdgpu_waves_per_eu(4,4)
// pins the register budget at 128 VGPR (512/4) so the allocator neither
// spills (round 1, 64-reg cap) nor rematerializes weight loads inside the
// loop (round 2, L2-BW-bound at ~2.1 ms).
__global__ __launch_bounds__(NTHREADS)
__attribute__((amdgpu_waves_per_eu(4, 4)))
void gru_fused(const float* __restrict__ x,
               const float* __restrict__ w_ih0,
               const float* __restrict__ w_ih_rest,
               const float* __restrict__ w_hh,
               const float* __restrict__ b_ih,
               const float* __restrict__ b_hh,
               const float* __restrict__ fc_w,
               const float* __restrict__ fc_b,
               float* __restrict__ out)
{
    // LDS layout (floats)
    extern __shared__ float smem[];
    float* xs   = smem;                    // 8192: x row as float4[2048]
    float* hst  = xs + 8192;               // 256:  h state per layer
    float* gbuf = hst + 256;               // 1344: 7*192 raw dot results
    float* w0s  = gbuf + 1344;             // 768:  layer-0 W_ih rows
    float* bihs = w0s + 768;               // 768:  b_ih (all 4 layers)
    float* bhhs = bihs + 768;              // 768:  b_hh (all 4 layers)

    const int tid = threadIdx.x;
    const int b   = blockIdx.x;

    // ---- stage x row, layer-0 weights, biases; zero h ----
    {
        const float4* xg = (const float4*)(x + (size_t)b * (T_LEN * 4));
        float4* xd = (float4*)xs;
        for (int i = tid; i < T_LEN; i += NTHREADS) xd[i] = xg[i];
    }
    if (tid < 192)                    ((float4*)w0s)[tid]        = ((const float4*)w_ih0)[tid];
    else if (tid < 384)               ((float4*)bihs)[tid - 192] = ((const float4*)b_ih)[tid - 192];
    else if (tid < 576)               ((float4*)bhhs)[tid - 384] = ((const float4*)b_hh)[tid - 384];
    if (tid < 256) hst[tid] = 0.0f;

    // ---- dot-thread identity ----
    const int g2   = tid >> 7;                  // 0..6
    const int r7   = tid & 127;
    const int c    = r7 >> 1;                   // 0..63
    const int half = r7 & 1;                    // 0/1
    const int src  = (g2 < 3) ? g2 : (g2 - 3);

    // ---- preload dot weights into registers (float4[3][8] = 96 VGPRs) ----
    float4 w4[3][8];
    {
        const float* wsrc = (g2 < 3) ? (w_ih_rest + g2 * (192 * 64))
                                     : (w_hh      + (g2 - 3) * (192 * 64));
        #pragma unroll
        for (int i = 0; i < 3; ++i) {
            const float4* p = (const float4*)(wsrc + (i * 64 + c) * 64 + half * 32);
            #pragma unroll
            for (int q = 0; q < 8; ++q) w4[i][q] = p[q];
        }
    }

    const int cl = tid >> 6;      // combine identity (tid<256)
    const int cc = tid & 63;
    __syncthreads();

    const float4* vb4 = (const float4*)(hst + src * 64 + half * 32);

    // ---- main diagonal loop ----
    for (int s = 0; s < T_LEN + 3; ++s) {
        // dot phase: 96 FMAs per thread, h vector broadcast from LDS
        float a0 = 0.f, a1 = 0.f, a2 = 0.f;
        #pragma unroll
        for (int q = 0; q < 8; ++q) {
            const float4 f = vb4[q];
            a0 = fmaf(f.x, w4[0][q].x, a0); a0 = fmaf(f.y, w4[0][q].y, a0);
            a0 = fmaf(f.z, w4[0][q].z, a0); a0 = fmaf(f.w, w4[0][q].w, a0);
            a1 = fmaf(f.x, w4[1][q].x, a1); a1 = fmaf(f.y, w4[1][q].y, a1);
            a1 = fmaf(f.z, w4[1][q].z, a1); a1 = fmaf(f.w, w4[1][q].w, a1);
            a2 = fmaf(f.x, w4[2][q].x, a2); a2 = fmaf(f.y, w4[2][q].y, a2);
            a2 = fmaf(f.z, w4[2][q].z, a2); a2 = fmaf(f.w, w4[2][q].w, a2);
        }
        a0 += __shfl_xor(a0, 1);
        a1 += __shfl_xor(a1, 1);
        a2 += __shfl_xor(a2, 1);
        if (half == 0) {
            gbuf[g2 * 192 +       c] = a0;
            gbuf[g2 * 192 +  64 + c] = a1;
            gbuf[g2 * 192 + 128 + c] = a2;
        }
        __syncthreads();

        // combine phase: 4 waves, one gate each, layer cl at t = s - cl
        if (tid < 256) {
            const int t = s - cl;
            if (t >= 0 && t < T_LEN) {
                float xr, xz, xn;
                if (cl == 0) {
                    const float4 xv = ((const float4*)xs)[t];
                    const float4 u0 = ((const float4*)w0s)[cc];
                    const float4 u1 = ((const float4*)w0s)[64 + cc];
                    const float4 u2 = ((const float4*)w0s)[128 + cc];
                    xr = bihs[cc]       + xv.x * u0.x + xv.y * u0.y + xv.z * u0.z + xv.w * u0.w;
                    xz = bihs[64 + cc]  + xv.x * u1.x + xv.y * u1.y + xv.z * u1.z + xv.w * u1.w;
                    xn = bihs[128 + cc] + xv.x * u2.x + xv.y * u2.y + xv.z * u2.z + xv.w * u2.w;
                } else {
                    xr = bihs[cl * 192 +       cc] + gbuf[(cl - 1) * 192 +       cc];
                    xz = bihs[cl * 192 +  64 + cc] + gbuf[(cl - 1) * 192 +  64 + cc];
                    xn = bihs[cl * 192 + 128 + cc] + gbuf[(cl - 1) * 192 + 128 + cc];
                }
                const float hr = bhhs[cl * 192 +       cc] + gbuf[(3 + cl) * 192 +       cc];
                const float hz = bhhs[cl * 192 +  64 + cc] + gbuf[(3 + cl) * 192 +  64 + cc];
                const float hn = bhhs[cl * 192 + 128 + cc] + gbuf[(3 + cl) * 192 + 128 + cc];
                const float hold = hst[cl * 64 + cc];

                const float r = 1.0f / (1.0f + __expf(-(xr + hr)));
                const float z = 1.0f / (1.0f + __expf(-(xz + hz)));
                const float e = __expf(2.0f * (xn + r * hn));
                const float n = 1.0f - 2.0f / (e + 1.0f);   // tanh
                hst[cl * 64 + cc] = n + z * (hold - n);      // (1-z)*n + z*h
            }
        }
        __syncthreads();
    }

    // ---- fused FC head on layer-3 final h ----
    if (tid < 5) {
        float acc = fc_b[tid];
        const float* wf = fc_w + tid * 64;
        #pragma unroll
        for (int k = 0; k < 64; ++k) acc = fmaf(hst[3 * 64 + k], wf[k], acc);
        out[(size_t)b * 5 + tid] = acc;
    }
}

extern "C" void kernel_launch(void* const* d_in, const int* in_sizes, int n_in,
                              void* d_out, int out_size, void* d_ws, size_t ws_size,
                              hipStream_t stream) {
    const float* x         = (const float*)d_in[0];
    const float* w_ih0     = (const float*)d_in[1];
    const float* w_ih_rest = (const float*)d_in[2];
    const float* w_hh      = (const float*)d_in[3];
    const float* b_ih      = (const float*)d_in[4];
    const float* b_hh      = (const float*)d_in[5];
    const float* fc_w      = (const float*)d_in[6];
    const float* fc_b      = (const float*)d_in[7];

    const size_t lds_bytes = (8192 + 256 + 1344 + 768 + 768 + 768) * sizeof(float);
    gru_fused<<<dim3(256), dim3(NTHREADS), lds_bytes, stream>>>(
        x, w_ih0, w_ih_rest, w_hh, b_ih, b_hh, fc_w, fc_b, (float*)d_out);
}